// Round 18
// baseline (59.770 us; speedup 1.0000x reference)
//
#include <hip/hip_runtime.h>

#define HW   16384
#define WID  128
#define HEI  128
#define CIN  64
#define OCH  64

typedef __attribute__((ext_vector_type(8))) short bf16x8;
typedef __attribute__((ext_vector_type(4))) short bf16x4;
typedef __attribute__((ext_vector_type(4))) float f32x4;

__device__ __forceinline__ unsigned short f2bf(float f) {
    unsigned u = __float_as_uint(f);
    u += 0x7FFF + ((u >> 16) & 1);          // RNE
    return (unsigned short)(u >> 16);
}
__device__ __forceinline__ float bf2f(short s) {
    return __uint_as_float(((unsigned)(unsigned short)s) << 16);
}

// ---------------- kernel P: x transpose + weight pack ----------------------
__global__ __launch_bounds__(256) void kprep(const float* __restrict__ x,
                                             const float* __restrict__ wdcn,
                                             const float* __restrict__ woff,
                                             unsigned short* __restrict__ xt,
                                             unsigned short* __restrict__ wpack,
                                             unsigned short* __restrict__ woffpack) {
    int blk = blockIdx.x;
    if (blk < 256) {
        int gp = blk * 256 + threadIdx.x;      // 0..65535 = (b, hw)
        int b = gp >> 14;
        int hw = gp & (HW - 1);
        const float* xb = x + (size_t)b * CIN * HW + hw;
        unsigned short* o = xt + ((size_t)gp << 6);
#pragma unroll
        for (int c8 = 0; c8 < 8; c8++) {
            bf16x8 v;
#pragma unroll
            for (int j = 0; j < 8; j++)
                v[j] = (short)f2bf(xb[(size_t)(c8 * 8 + j) * HW]);
            *(bf16x8*)(o + c8 * 8) = v;
        }
    } else {
        int t = (blk - 256) * 256 + threadIdx.x;   // 0..55295
        if (t < 36864) {
            int j  = t & 7;
            int l  = (t >> 3) & 63;
            int nt = (t >> 9) & 3;
            int s  = t >> 11;                      // 0..17
            int k  = s * 32 + (l >> 4) * 8 + j;
            int o  = nt * 16 + (l & 15);
            int tap = k >> 6, c = k & 63;
            wpack[t] = f2bf(wdcn[o * 576 + c * 9 + tap]);
        } else {
            int u  = t - 36864;                    // 0..18431
            int j  = u & 7;
            int l  = (u >> 3) & 63;
            int nt = (u >> 9) & 1;
            int s  = u >> 10;                      // 0..17
            int k  = s * 32 + (l >> 4) * 8 + j;
            int o  = nt * 16 + (l & 15);
            int tap = k >> 6, c = k & 63;
            float v = (o < 18) ? woff[o * 576 + c * 9 + tap] : 0.f;
            woffpack[u] = f2bf(v);
        }
    }
}

// ---------------- kernel B: offset conv + deformable sample + MFMA ---------
// block = 4 waves, 32 consecutive-w pixels.  3 barriers.
// LDS (39168 B -> 4 blocks/CU):
//   [0..36863]     phase 0/0b: 3x34 window (XOR-swz by col);
//                  phase B/MFMA: patch bf16 [32 px][576 k] pitch 1152 B
//   [36864..39167] offLds f32 [32 px][18]
// Phase B: 1-deep pipeline via two statically-named register sets (a/b),
// macro-expanded — no lambda/references, so nothing can go to scratch.
__global__ __launch_bounds__(256, 4) void kdcn(const unsigned short* __restrict__ xt,
                                               const unsigned short* __restrict__ wpack,
                                               const unsigned short* __restrict__ woffpack,
                                               const float* __restrict__ boff,
                                               const float* __restrict__ bdcn,
                                               unsigned short* __restrict__ convb,
                                               float* __restrict__ part) {
    __shared__ __align__(16) unsigned char smem[39168];

    int tid = threadIdx.x;
    int lane = tid & 63, wave = tid >> 6;
    int lr = lane & 15, hi = lane >> 4;

    int pixg = blockIdx.x * 32;
    int b = pixg >> 14;                 // uniform
    int hwb = pixg & (HW - 1);
    int h = hwb >> 7;                   // uniform (32 | 128)
    int w0 = hwb & (WID - 1);

    // ---- phase 0: stage 3x34-col window (zero-padded) into LDS ------------
    {
        const unsigned char* xb = (const unsigned char*)xt + (((size_t)b * HW) << 7);
#pragma unroll
        for (int i = 0; i < 4; i++) {
            int item = tid + i * 256;
            if (item < 816) {
                int sub  = item & 7;
                int cell = item >> 3;          // 0..101
                int colw = cell % 34;
                int roww = cell / 34;
                int sy = h + roww - 1;
                int sx = w0 + colw - 1;
                bool ok = ((unsigned)sy < HEI) && ((unsigned)sx < WID);
                bf16x8 v = {0, 0, 0, 0, 0, 0, 0, 0};
                if (ok) v = *(const bf16x8*)(xb + ((sy * WID + sx) << 7) + sub * 16);
                *(bf16x8*)(smem + ((unsigned)((roww * 34 + colw) * 128 + sub * 16)
                                   ^ ((unsigned)(colw & 7) << 4))) = v;
            }
        }
    }
    __syncthreads();

    // ---- phase 0b: offset conv via MFMA; D[32 px][18 oc] -> offLds --------
    {
        int mw = wave & 1, nw = wave >> 1;
        int pxr = mw * 16 + lr;                // A-row pixel
        int oc = nw * 16 + lr;
        float ob = (oc < 18) ? boff[oc] : 0.f;
        f32x4 oacc = {ob, ob, ob, ob};
        const unsigned short* wop = woffpack + (size_t)(nw * 64 + lane) * 8;
#pragma unroll
        for (int s = 0; s < 18; s++) {
            int tap = s >> 1;
            int ky = tap / 3;
            int kx = tap - ky * 3;
            int colw = pxr + kx;
            unsigned addr = (unsigned)((ky * 34 + colw) * 128 + (s & 1) * 64 + hi * 16)
                          ^ ((unsigned)(colw & 7) << 4);
            bf16x8 a  = *(const bf16x8*)(smem + addr);
            bf16x8 wf = *(const bf16x8*)(wop + (size_t)s * 1024);
            oacc = __builtin_amdgcn_mfma_f32_16x16x32_bf16(a, wf, oacc, 0, 0, 0);
        }
        float* offLds = (float*)(smem + 36864);
        if (oc < 18) {
#pragma unroll
            for (int r = 0; r < 4; r++)
                offLds[(mw * 16 + hi * 4 + r) * 18 + oc] = oacc[r];
        }
    }

    // ---- B fragments + bias (o = wave*16 + lr)
    bf16x8 bfrag[18];
    const unsigned short* wp = wpack + (size_t)(wave * 64 + lane) * 8;
#pragma unroll
    for (int s = 0; s < 18; s++)
        bfrag[s] = *(const bf16x8*)(wp + (size_t)s * 2048);
    float bias = bdcn[wave * 16 + lr];
    __syncthreads();

    // ---- phase B: 1-deep pipelined gather + interp + pack into patch ------
    {
        int g = lane >> 3, sub = lane & 7;
        int px = wave * 8 + g;
        int w = w0 + px;
        const unsigned char* xtb =
            (const unsigned char*)xt + (((size_t)b * HW) << 7) + sub * 16;
        unsigned char* prow = smem + px * 1152;
        unsigned swz = (unsigned)((px & 7) << 4);
        const float* offL = (const float*)(smem + 36864) + px * 18;

        float2 offv[9];
#pragma unroll
        for (int t = 0; t < 9; t++)
            offv[t] = *((const float2*)offL + t);

        float  w00a, w01a, w10a, w11a, w00b, w01b, w10b, w11b;
        bf16x8 c00a, c01a, c10a, c11a, c00b, c01b, c10b, c11b;

#define TAPLOAD(T, S) do {                                                   \
        float py_  = offv[T].x + (float)(h + (T) / 3 - 1);                   \
        float pxf_ = offv[T].y + (float)(w + (T) % 3 - 1);                   \
        float y0f_ = floorf(py_), x0f_ = floorf(pxf_);                       \
        float wy_ = py_ - y0f_, wx_ = pxf_ - x0f_;                           \
        int y0_ = (int)y0f_, x0_ = (int)x0f_;                                \
        float wy0_ = ((unsigned)y0_       < HEI) ? 1.f - wy_ : 0.f;          \
        float wy1_ = ((unsigned)(y0_ + 1) < HEI) ? wy_       : 0.f;          \
        float wx0_ = ((unsigned)x0_       < WID) ? 1.f - wx_ : 0.f;          \
        float wx1_ = ((unsigned)(x0_ + 1) < WID) ? wx_       : 0.f;          \
        int yc0_ = min(max(y0_, 0),     HEI - 1) * WID;                      \
        int yc1_ = min(max(y0_ + 1, 0), HEI - 1) * WID;                      \
        int xc0_ = min(max(x0_, 0),     WID - 1);                            \
        int xc1_ = min(max(x0_ + 1, 0), WID - 1);                            \
        w00##S = wy0_ * wx0_; w01##S = wy0_ * wx1_;                          \
        w10##S = wy1_ * wx0_; w11##S = wy1_ * wx1_;                          \
        c00##S = *(const bf16x8*)(xtb + ((yc0_ + xc0_) << 7));               \
        c01##S = *(const bf16x8*)(xtb + ((yc0_ + xc1_) << 7));               \
        c10##S = *(const bf16x8*)(xtb + ((yc1_ + xc0_) << 7));               \
        c11##S = *(const bf16x8*)(xtb + ((yc1_ + xc1_) << 7));               \
    } while (0)

#define TAPSTORE(T, S) do {                                                  \
        bf16x8 v_;                                                           \
        _Pragma("unroll")                                                    \
        for (int j = 0; j < 8; j++) {                                        \
            float sv_ = w00##S * bf2f(c00##S[j]) + w01##S * bf2f(c01##S[j])  \
                      + w10##S * bf2f(c10##S[j]) + w11##S * bf2f(c11##S[j]); \
            v_[j] = (short)f2bf(sv_);                                        \
        }                                                                    \
        *(bf16x8*)(prow + ((unsigned)((T) * 128 + sub * 16) ^ swz)) = v_;    \
    } while (0)

        TAPLOAD(0, a);
        TAPLOAD(1, b); TAPSTORE(0, a);
        TAPLOAD(2, a); TAPSTORE(1, b);
        TAPLOAD(3, b); TAPSTORE(2, a);
        TAPLOAD(4, a); TAPSTORE(3, b);
        TAPLOAD(5, b); TAPSTORE(4, a);
        TAPLOAD(6, a); TAPSTORE(5, b);
        TAPLOAD(7, b); TAPSTORE(6, a);
        TAPLOAD(8, a); TAPSTORE(7, b);
        TAPSTORE(8, a);
#undef TAPLOAD
#undef TAPSTORE
    }
    __syncthreads();

    // ---- main MFMA: D[32 px][64 o], wave owns o-tile = wave
    f32x4 acc0 = {bias, bias, bias, bias};
    f32x4 acc1 = acc0;
    unsigned swzr = (unsigned)((lr & 7) << 4);
#pragma unroll
    for (int s = 0; s < 18; s++) {
        unsigned inblk = (unsigned)((s >> 1) * 128)
                       + (((unsigned)((s & 1) * 64 + hi * 16)) ^ swzr);
        bf16x8 a0 = *(const bf16x8*)(smem + lr * 1152 + inblk);
        bf16x8 a1 = *(const bf16x8*)(smem + (16 + lr) * 1152 + inblk);
        acc0 = __builtin_amdgcn_mfma_f32_16x16x32_bf16(a0, bfrag[s], acc0, 0, 0, 0);
        acc1 = __builtin_amdgcn_mfma_f32_16x16x32_bf16(a1, bfrag[s], acc1, 0, 0, 0);
    }

    // ---- direct C stores (bf16): lane holds px = hi*4..+3 of o = wave*16+lr
    {
        int o = wave * 16 + lr;
        unsigned short* cb = convb + ((size_t)b * OCH + o) * HW + hwb + hi * 4;
        bf16x4 v0, v1;
#pragma unroll
        for (int r = 0; r < 4; r++) { v0[r] = (short)f2bf(acc0[r]);
                                      v1[r] = (short)f2bf(acc1[r]); }
        *(bf16x4*)cb        = v0;
        *(bf16x4*)(cb + 16) = v1;
    }

    // ---- BN partials (no barrier follows; plain stores, no contention) ----
    {
        float s  = acc0[0] + acc0[1] + acc0[2] + acc0[3]
                 + acc1[0] + acc1[1] + acc1[2] + acc1[3];
        float s2 = acc0[0]*acc0[0] + acc0[1]*acc0[1] + acc0[2]*acc0[2] + acc0[3]*acc0[3]
                 + acc1[0]*acc1[0] + acc1[1]*acc1[1] + acc1[2]*acc1[2] + acc1[3]*acc1[3];
        s  += __shfl_xor(s, 16);  s2 += __shfl_xor(s2, 16);
        s  += __shfl_xor(s, 32);  s2 += __shfl_xor(s2, 32);
        if (hi == 0) {
            int c = wave * 16 + lr;
            part[(size_t)c * 2048 + blockIdx.x]        = s;
            part[(size_t)(64 + c) * 2048 + blockIdx.x] = s2;
        }
    }
}

// ---------------- kernel R: reduce partials -> stats[128] ------------------
__global__ __launch_bounds__(256) void kred(const float* __restrict__ part,
                                            float* __restrict__ stats) {
    int row = blockIdx.x;                 // 0..127
    int tid = threadIdx.x;
    const float* p = part + (size_t)row * 2048;
    float s = 0.f;
#pragma unroll
    for (int i = 0; i < 8; i++) s += p[tid + i * 256];
#pragma unroll
    for (int d = 1; d < 64; d <<= 1) s += __shfl_xor(s, d);
    __shared__ float red[4];
    if ((tid & 63) == 0) red[tid >> 6] = s;
    __syncthreads();
    if (tid == 0) stats[row] = red[0] + red[1] + red[2] + red[3];
}

// ---------------- kernel D: finalize stats + normalize + relu --------------
__global__ __launch_bounds__(256) void kapply(const unsigned short* __restrict__ convb,
                                              float* __restrict__ out,
                                              const float* __restrict__ stats,
                                              const float* __restrict__ gamma,
                                              const float* __restrict__ beta) {
    int t = blockIdx.x * 256 + threadIdx.x;   // < 1048576 groups of 4
    int c = (t >> 12) & 63;
    float mean = stats[c] * (1.f / 65536.f);
    float var  = stats[64 + c] * (1.f / 65536.f) - mean * mean;
    float rstd = rsqrtf(var + 1e-5f);
    float sc = rstd * gamma[c];
    float sh = beta[c] - mean * sc;
    bf16x4 v = *(const bf16x4*)(convb + (size_t)t * 4);
    float4 r;
    r.x = fmaxf(bf2f(v[0]) * sc + sh, 0.f);
    r.y = fmaxf(bf2f(v[1]) * sc + sh, 0.f);
    r.z = fmaxf(bf2f(v[2]) * sc + sh, 0.f);
    r.w = fmaxf(bf2f(v[3]) * sc + sh, 0.f);
    ((float4*)out)[t] = r;
}

// ---------------- launch ---------------------------------------------------
extern "C" void kernel_launch(void* const* d_in, const int* in_sizes, int n_in,
                              void* d_out, int out_size, void* d_ws, size_t ws_size,
                              hipStream_t stream) {
    const float* x     = (const float*)d_in[0];
    const float* woff  = (const float*)d_in[1];
    const float* boff  = (const float*)d_in[2];
    const float* wdcn  = (const float*)d_in[3];
    const float* bdcn  = (const float*)d_in[4];
    const float* gamma = (const float*)d_in[5];
    const float* beta  = (const float*)d_in[6];
    float* out = (float*)d_out;

    // ws layout (bytes): xt 8MB | wpack 72KB | woffpack 36KB | part 1MB |
    //                    stats 512B | convb 8MB
    unsigned char* ws = (unsigned char*)d_ws;
    unsigned short* xt       = (unsigned short*)ws;            // 4,194,304 ush
    unsigned short* wpack    = (unsigned short*)(ws + 8388608);//    36,864 ush
    unsigned short* woffpack = (unsigned short*)(ws + 8462336);//    18,432 ush
    float*          part     = (float*)(ws + 8499200);         //   262,144 f
    float*          stats    = (float*)(ws + 9547776);         //       128 f
    unsigned short* convb    = (unsigned short*)(ws + 9548288);// 4,194,304 ush

    hipLaunchKernelGGL(kprep,  dim3(472),  dim3(256), 0, stream,
                       x, wdcn, woff, xt, wpack, woffpack);
    hipLaunchKernelGGL(kdcn,   dim3(2048), dim3(256), 0, stream,
                       xt, wpack, woffpack, boff, bdcn, convb, part);
    hipLaunchKernelGGL(kred,   dim3(128),  dim3(256), 0, stream, part, stats);
    hipLaunchKernelGGL(kapply, dim3(4096), dim3(256), 0, stream,
                       convb, out, stats, gamma, beta);
}

// Round 19
// 49.400 us; speedup vs baseline: 1.2099x; 1.2099x over previous
//
#include <hip/hip_runtime.h>

#define HW   16384
#define WID  128
#define HEI  128
#define CIN  64
#define OCH  64

typedef __attribute__((ext_vector_type(8))) short bf16x8;
typedef __attribute__((ext_vector_type(4))) short bf16x4;
typedef __attribute__((ext_vector_type(4))) float f32x4;

__device__ __forceinline__ unsigned short f2bf(float f) {
    unsigned u = __float_as_uint(f);
    u += 0x7FFF + ((u >> 16) & 1);          // RNE
    return (unsigned short)(u >> 16);
}
__device__ __forceinline__ float bf2f(short s) {
    return __uint_as_float(((unsigned)(unsigned short)s) << 16);
}

// ---------------- kernel P: x transpose + weight pack ----------------------
__global__ __launch_bounds__(256) void kprep(const float* __restrict__ x,
                                             const float* __restrict__ wdcn,
                                             const float* __restrict__ woff,
                                             unsigned short* __restrict__ xt,
                                             unsigned short* __restrict__ wpack,
                                             unsigned short* __restrict__ woffpack) {
    int blk = blockIdx.x;
    if (blk < 256) {
        int gp = blk * 256 + threadIdx.x;      // 0..65535 = (b, hw)
        int b = gp >> 14;
        int hw = gp & (HW - 1);
        const float* xb = x + (size_t)b * CIN * HW + hw;
        unsigned short* o = xt + ((size_t)gp << 6);
#pragma unroll
        for (int c8 = 0; c8 < 8; c8++) {
            bf16x8 v;
#pragma unroll
            for (int j = 0; j < 8; j++)
                v[j] = (short)f2bf(xb[(size_t)(c8 * 8 + j) * HW]);
            *(bf16x8*)(o + c8 * 8) = v;
        }
    } else {
        int t = (blk - 256) * 256 + threadIdx.x;   // 0..55295
        if (t < 36864) {
            int j  = t & 7;
            int l  = (t >> 3) & 63;
            int nt = (t >> 9) & 3;
            int s  = t >> 11;                      // 0..17
            int k  = s * 32 + (l >> 4) * 8 + j;
            int o  = nt * 16 + (l & 15);
            int tap = k >> 6, c = k & 63;
            wpack[t] = f2bf(wdcn[o * 576 + c * 9 + tap]);
        } else {
            int u  = t - 36864;                    // 0..18431
            int j  = u & 7;
            int l  = (u >> 3) & 63;
            int nt = (u >> 9) & 1;
            int s  = u >> 10;                      // 0..17
            int k  = s * 32 + (l >> 4) * 8 + j;
            int o  = nt * 16 + (l & 15);
            int tap = k >> 6, c = k & 63;
            float v = (o < 18) ? woff[o * 576 + c * 9 + tap] : 0.f;
            woffpack[u] = f2bf(v);
        }
    }
}

// ---------------- kernel B: offset conv + deformable sample + MFMA ---------
// block = 4 waves, 32 consecutive-w pixels.  3 barriers.
// LDS (39168 B -> 4 blocks/CU):
//   [0..36863]     phase 0/0b: 3x34 window (XOR-swz by col);
//                  phase B/MFMA: patch bf16 [32 px][576 k] pitch 1152 B
//   [36864..39167] offLds f32 [32 px][18]
// Phase B: 1-deep pipeline, two statically-named register sets; offsets read
// from LDS per tap; bfrag loads deferred past phase B to keep live<64 VGPRs.
__global__ __launch_bounds__(256, 4) void kdcn(const unsigned short* __restrict__ xt,
                                               const unsigned short* __restrict__ wpack,
                                               const unsigned short* __restrict__ woffpack,
                                               const float* __restrict__ boff,
                                               const float* __restrict__ bdcn,
                                               unsigned short* __restrict__ convb,
                                               float* __restrict__ part) {
    __shared__ __align__(16) unsigned char smem[39168];

    int tid = threadIdx.x;
    int lane = tid & 63, wave = tid >> 6;
    int lr = lane & 15, hi = lane >> 4;

    int pixg = blockIdx.x * 32;
    int b = pixg >> 14;                 // uniform
    int hwb = pixg & (HW - 1);
    int h = hwb >> 7;                   // uniform (32 | 128)
    int w0 = hwb & (WID - 1);

    // ---- phase 0: stage 3x34-col window (zero-padded) into LDS ------------
    {
        const unsigned char* xb = (const unsigned char*)xt + (((size_t)b * HW) << 7);
#pragma unroll
        for (int i = 0; i < 4; i++) {
            int item = tid + i * 256;
            if (item < 816) {
                int sub  = item & 7;
                int cell = item >> 3;          // 0..101
                int colw = cell % 34;
                int roww = cell / 34;
                int sy = h + roww - 1;
                int sx = w0 + colw - 1;
                bool ok = ((unsigned)sy < HEI) && ((unsigned)sx < WID);
                bf16x8 v = {0, 0, 0, 0, 0, 0, 0, 0};
                if (ok) v = *(const bf16x8*)(xb + ((sy * WID + sx) << 7) + sub * 16);
                *(bf16x8*)(smem + ((unsigned)((roww * 34 + colw) * 128 + sub * 16)
                                   ^ ((unsigned)(colw & 7) << 4))) = v;
            }
        }
    }
    __syncthreads();

    // ---- phase 0b: offset conv via MFMA; D[32 px][18 oc] -> offLds --------
    {
        int mw = wave & 1, nw = wave >> 1;
        int pxr = mw * 16 + lr;                // A-row pixel
        int oc = nw * 16 + lr;
        float ob = (oc < 18) ? boff[oc] : 0.f;
        f32x4 oacc = {ob, ob, ob, ob};
        const unsigned short* wop = woffpack + (size_t)(nw * 64 + lane) * 8;
#pragma unroll
        for (int s = 0; s < 18; s++) {
            int tap = s >> 1;
            int ky = tap / 3;
            int kx = tap - ky * 3;
            int colw = pxr + kx;
            unsigned addr = (unsigned)((ky * 34 + colw) * 128 + (s & 1) * 64 + hi * 16)
                          ^ ((unsigned)(colw & 7) << 4);
            bf16x8 a  = *(const bf16x8*)(smem + addr);
            bf16x8 wf = *(const bf16x8*)(wop + (size_t)s * 1024);
            oacc = __builtin_amdgcn_mfma_f32_16x16x32_bf16(a, wf, oacc, 0, 0, 0);
        }
        float* offLds = (float*)(smem + 36864);
        if (oc < 18) {
#pragma unroll
            for (int r = 0; r < 4; r++)
                offLds[(mw * 16 + hi * 4 + r) * 18 + oc] = oacc[r];
        }
    }
    __syncthreads();

    // ---- phase B: 1-deep pipelined gather + interp + pack into patch ------
    {
        int g = lane >> 3, sub = lane & 7;
        int px = wave * 8 + g;
        int w = w0 + px;
        const unsigned char* xtb =
            (const unsigned char*)xt + (((size_t)b * HW) << 7) + sub * 16;
        unsigned char* prow = smem + px * 1152;
        unsigned swz = (unsigned)((px & 7) << 4);
        const float2* offL2 = (const float2*)((const float*)(smem + 36864) + px * 18);

        float  w00a, w01a, w10a, w11a, w00b, w01b, w10b, w11b;
        bf16x8 c00a, c01a, c10a, c11a, c00b, c01b, c10b, c11b;

#define TAPLOAD(T, S) do {                                                   \
        float2 o_ = offL2[T];                                                \
        float py_  = o_.x + (float)(h + (T) / 3 - 1);                        \
        float pxf_ = o_.y + (float)(w + (T) % 3 - 1);                        \
        float y0f_ = floorf(py_), x0f_ = floorf(pxf_);                       \
        float wy_ = py_ - y0f_, wx_ = pxf_ - x0f_;                           \
        int y0_ = (int)y0f_, x0_ = (int)x0f_;                                \
        float wy0_ = ((unsigned)y0_       < HEI) ? 1.f - wy_ : 0.f;          \
        float wy1_ = ((unsigned)(y0_ + 1) < HEI) ? wy_       : 0.f;          \
        float wx0_ = ((unsigned)x0_       < WID) ? 1.f - wx_ : 0.f;          \
        float wx1_ = ((unsigned)(x0_ + 1) < WID) ? wx_       : 0.f;          \
        int yc0_ = min(max(y0_, 0),     HEI - 1) * WID;                      \
        int yc1_ = min(max(y0_ + 1, 0), HEI - 1) * WID;                      \
        int xc0_ = min(max(x0_, 0),     WID - 1);                            \
        int xc1_ = min(max(x0_ + 1, 0), WID - 1);                            \
        w00##S = wy0_ * wx0_; w01##S = wy0_ * wx1_;                          \
        w10##S = wy1_ * wx0_; w11##S = wy1_ * wx1_;                          \
        c00##S = *(const bf16x8*)(xtb + ((yc0_ + xc0_) << 7));               \
        c01##S = *(const bf16x8*)(xtb + ((yc0_ + xc1_) << 7));               \
        c10##S = *(const bf16x8*)(xtb + ((yc1_ + xc0_) << 7));               \
        c11##S = *(const bf16x8*)(xtb + ((yc1_ + xc1_) << 7));               \
    } while (0)

#define TAPSTORE(T, S) do {                                                  \
        bf16x8 v_;                                                           \
        _Pragma("unroll")                                                    \
        for (int j = 0; j < 8; j++) {                                        \
            float sv_ = w00##S * bf2f(c00##S[j]) + w01##S * bf2f(c01##S[j])  \
                      + w10##S * bf2f(c10##S[j]) + w11##S * bf2f(c11##S[j]); \
            v_[j] = (short)f2bf(sv_);                                        \
        }                                                                    \
        *(bf16x8*)(prow + ((unsigned)((T) * 128 + sub * 16) ^ swz)) = v_;    \
    } while (0)

        TAPLOAD(0, a);
        TAPLOAD(1, b); TAPSTORE(0, a);
        TAPLOAD(2, a); TAPSTORE(1, b);
        TAPLOAD(3, b); TAPSTORE(2, a);
        TAPLOAD(4, a); TAPSTORE(3, b);
        TAPLOAD(5, b); TAPSTORE(4, a);
        TAPLOAD(6, a); TAPSTORE(5, b);
        TAPLOAD(7, b); TAPSTORE(6, a);
        TAPLOAD(8, a); TAPSTORE(7, b);
        TAPSTORE(8, a);
#undef TAPLOAD
#undef TAPSTORE
    }
    __syncthreads();

    // ---- B fragments + bias (deferred here to keep phase-B live state low)
    bf16x8 bfrag[18];
    const unsigned short* wp = wpack + (size_t)(wave * 64 + lane) * 8;
#pragma unroll
    for (int s = 0; s < 18; s++)
        bfrag[s] = *(const bf16x8*)(wp + (size_t)s * 2048);
    float bias = bdcn[wave * 16 + lr];

    // ---- main MFMA: D[32 px][64 o], wave owns o-tile = wave
    f32x4 acc0 = {bias, bias, bias, bias};
    f32x4 acc1 = acc0;
    unsigned swzr = (unsigned)((lr & 7) << 4);
#pragma unroll
    for (int s = 0; s < 18; s++) {
        unsigned inblk = (unsigned)((s >> 1) * 128)
                       + (((unsigned)((s & 1) * 64 + hi * 16)) ^ swzr);
        bf16x8 a0 = *(const bf16x8*)(smem + lr * 1152 + inblk);
        bf16x8 a1 = *(const bf16x8*)(smem + (16 + lr) * 1152 + inblk);
        acc0 = __builtin_amdgcn_mfma_f32_16x16x32_bf16(a0, bfrag[s], acc0, 0, 0, 0);
        acc1 = __builtin_amdgcn_mfma_f32_16x16x32_bf16(a1, bfrag[s], acc1, 0, 0, 0);
    }

    // ---- direct C stores (bf16): lane holds px = hi*4..+3 of o = wave*16+lr
    {
        int o = wave * 16 + lr;
        unsigned short* cb = convb + ((size_t)b * OCH + o) * HW + hwb + hi * 4;
        bf16x4 v0, v1;
#pragma unroll
        for (int r = 0; r < 4; r++) { v0[r] = (short)f2bf(acc0[r]);
                                      v1[r] = (short)f2bf(acc1[r]); }
        *(bf16x4*)cb        = v0;
        *(bf16x4*)(cb + 16) = v1;
    }

    // ---- BN partials (no barrier follows; plain stores, no contention) ----
    {
        float s  = acc0[0] + acc0[1] + acc0[2] + acc0[3]
                 + acc1[0] + acc1[1] + acc1[2] + acc1[3];
        float s2 = acc0[0]*acc0[0] + acc0[1]*acc0[1] + acc0[2]*acc0[2] + acc0[3]*acc0[3]
                 + acc1[0]*acc1[0] + acc1[1]*acc1[1] + acc1[2]*acc1[2] + acc1[3]*acc1[3];
        s  += __shfl_xor(s, 16);  s2 += __shfl_xor(s2, 16);
        s  += __shfl_xor(s, 32);  s2 += __shfl_xor(s2, 32);
        if (hi == 0) {
            int c = wave * 16 + lr;
            part[(size_t)c * 2048 + blockIdx.x]        = s;
            part[(size_t)(64 + c) * 2048 + blockIdx.x] = s2;
        }
    }
}

// ---------------- kernel R: reduce partials -> stats[128] ------------------
__global__ __launch_bounds__(256) void kred(const float* __restrict__ part,
                                            float* __restrict__ stats) {
    int row = blockIdx.x;                 // 0..127
    int tid = threadIdx.x;
    const float* p = part + (size_t)row * 2048;
    float s = 0.f;
#pragma unroll
    for (int i = 0; i < 8; i++) s += p[tid + i * 256];
#pragma unroll
    for (int d = 1; d < 64; d <<= 1) s += __shfl_xor(s, d);
    __shared__ float red[4];
    if ((tid & 63) == 0) red[tid >> 6] = s;
    __syncthreads();
    if (tid == 0) stats[row] = red[0] + red[1] + red[2] + red[3];
}

// ---------------- kernel D: finalize stats + normalize + relu --------------
__global__ __launch_bounds__(256) void kapply(const unsigned short* __restrict__ convb,
                                              float* __restrict__ out,
                                              const float* __restrict__ stats,
                                              const float* __restrict__ gamma,
                                              const float* __restrict__ beta) {
    int t = blockIdx.x * 256 + threadIdx.x;   // < 1048576 groups of 4
    int c = (t >> 12) & 63;
    float mean = stats[c] * (1.f / 65536.f);
    float var  = stats[64 + c] * (1.f / 65536.f) - mean * mean;
    float rstd = rsqrtf(var + 1e-5f);
    float sc = rstd * gamma[c];
    float sh = beta[c] - mean * sc;
    bf16x4 v = *(const bf16x4*)(convb + (size_t)t * 4);
    float4 r;
    r.x = fmaxf(bf2f(v[0]) * sc + sh, 0.f);
    r.y = fmaxf(bf2f(v[1]) * sc + sh, 0.f);
    r.z = fmaxf(bf2f(v[2]) * sc + sh, 0.f);
    r.w = fmaxf(bf2f(v[3]) * sc + sh, 0.f);
    ((float4*)out)[t] = r;
}

// ---------------- launch ---------------------------------------------------
extern "C" void kernel_launch(void* const* d_in, const int* in_sizes, int n_in,
                              void* d_out, int out_size, void* d_ws, size_t ws_size,
                              hipStream_t stream) {
    const float* x     = (const float*)d_in[0];
    const float* woff  = (const float*)d_in[1];
    const float* boff  = (const float*)d_in[2];
    const float* wdcn  = (const float*)d_in[3];
    const float* bdcn  = (const float*)d_in[4];
    const float* gamma = (const float*)d_in[5];
    const float* beta  = (const float*)d_in[6];
    float* out = (float*)d_out;

    // ws layout (bytes): xt 8MB | wpack 72KB | woffpack 36KB | part 1MB |
    //                    stats 512B | convb 8MB
    unsigned char* ws = (unsigned char*)d_ws;
    unsigned short* xt       = (unsigned short*)ws;            // 4,194,304 ush
    unsigned short* wpack    = (unsigned short*)(ws + 8388608);//    36,864 ush
    unsigned short* woffpack = (unsigned short*)(ws + 8462336);//    18,432 ush
    float*          part     = (float*)(ws + 8499200);         //   262,144 f
    float*          stats    = (float*)(ws + 9547776);         //       128 f
    unsigned short* convb    = (unsigned short*)(ws + 9548288);// 4,194,304 ush

    hipLaunchKernelGGL(kprep,  dim3(472),  dim3(256), 0, stream,
                       x, wdcn, woff, xt, wpack, woffpack);
    hipLaunchKernelGGL(kdcn,   dim3(2048), dim3(256), 0, stream,
                       xt, wpack, woffpack, boff, bdcn, convb, part);
    hipLaunchKernelGGL(kred,   dim3(128),  dim3(256), 0, stream, part, stats);
    hipLaunchKernelGGL(kapply, dim3(4096), dim3(256), 0, stream,
                       convb, out, stats, gamma, beta);
}